// Round 10
// baseline (508.016 us; speedup 1.0000x reference)
//
#include <hip/hip_runtime.h>
#include <hip/hip_bf16.h>

typedef float f32x4 __attribute__((ext_vector_type(4)));
typedef int i32x4v __attribute__((ext_vector_type(4)));
typedef int i32x8v __attribute__((ext_vector_type(8)));

#define IGNORE_INDEX (-100)
#define N_ROWS 4096
#define H_DIM  1024
#define V_DIM  32000

#define BM 128
#define BN 256
#define BK 128                 /* fp8 elements = bytes; one mfma_scale K */
#define NKT (H_DIM / BK)       /* 8 */
#define CT_NUM (V_DIM / BN)    /* 125 */
#define RT_NUM (N_ROWS / BM)   /* 32 */
#define SCALE1 0x7f7f7f7f      /* 4x e8m0 = 127 -> x1.0 */

// ---------- fused prep: cast x -> fp8 (blocks < XB8) + transpose-cast w ----------
#define XB8 (N_ROWS * H_DIM / (256 * 16))  /* 1024 */
__global__ __launch_bounds__(256) void k_prep(const float* __restrict__ x,
                                              const float* __restrict__ w,
                                              unsigned char* __restrict__ x8,
                                              unsigned char* __restrict__ wT8) {
  __shared__ float tile[128][65];
  const int t = threadIdx.x;
  if (blockIdx.x < XB8) {
    size_t i = ((size_t)blockIdx.x * 256 + t) * 16;
    const float4* xp = (const float4*)(x + i);
    float4 f0 = xp[0], f1 = xp[1], f2 = xp[2], f3 = xp[3];
    int4 o;
    int r;
    r = __builtin_amdgcn_cvt_pk_fp8_f32(f0.x, f0.y, 0, false);
    r = __builtin_amdgcn_cvt_pk_fp8_f32(f0.z, f0.w, r, true);
    o.x = r;
    r = __builtin_amdgcn_cvt_pk_fp8_f32(f1.x, f1.y, 0, false);
    r = __builtin_amdgcn_cvt_pk_fp8_f32(f1.z, f1.w, r, true);
    o.y = r;
    r = __builtin_amdgcn_cvt_pk_fp8_f32(f2.x, f2.y, 0, false);
    r = __builtin_amdgcn_cvt_pk_fp8_f32(f2.z, f2.w, r, true);
    o.z = r;
    r = __builtin_amdgcn_cvt_pk_fp8_f32(f3.x, f3.y, 0, false);
    r = __builtin_amdgcn_cvt_pk_fp8_f32(f3.z, f3.w, r, true);
    o.w = r;
    *(int4*)(x8 + i) = o;
    return;
  }
  const int b = blockIdx.x - XB8;
  const int v0 = (b % (V_DIM / 64)) * 64;
  const int k0 = (b / (V_DIM / 64)) * 128;
  {
    const int vq = t & 15;    // float4 index (16 x 4 = 64 floats/row)
    const int kr = t >> 4;    // 0..15
#pragma unroll
    for (int p = 0; p < 128; p += 16) {
      float4 v = *(const float4*)(w + (size_t)(k0 + kr + p) * V_DIM + v0 + vq * 4);
      tile[kr + p][vq * 4 + 0] = v.x;
      tile[kr + p][vq * 4 + 1] = v.y;
      tile[kr + p][vq * 4 + 2] = v.z;
      tile[kr + p][vq * 4 + 3] = v.w;
    }
  }
  __syncthreads();
  {
    const int vr = t >> 2;    // 0..63
    const int kq2 = t & 3;
#pragma unroll
    for (int h = 0; h < 2; ++h) {
      const int d4 = kq2 + h * 4;   // int4 index within 128B k-run
      int4 o;
      int r;
#pragma unroll
      for (int d = 0; d < 4; ++d) {
        r = __builtin_amdgcn_cvt_pk_fp8_f32(tile[d4 * 16 + d * 4 + 0][vr],
                                            tile[d4 * 16 + d * 4 + 1][vr], 0, false);
        r = __builtin_amdgcn_cvt_pk_fp8_f32(tile[d4 * 16 + d * 4 + 2][vr],
                                            tile[d4 * 16 + d * 4 + 3][vr], r, true);
        ((int*)&o)[d] = r;
      }
      *(int4*)(wT8 + (size_t)(v0 + vr) * H_DIM + k0 + d4 * 16) = o;
    }
  }
}

// ------------- fused MX-fp8 GEMM + per-row max/sumexp ------------------------
// R8 LESSON: 128x256/256thr/96KB-LDS was clean (VGPR 200, no spill) but
// 1 block/CU, 1 wave/SIMD (Occupancy 11%) -> every barrier/vmem stall fully
// exposed, MfmaUtil 22%. Also LDS carried 96 KB/K-tile of ds_read_b128 with
// a structural 8-way bank pattern.
//
// THIS ROUND: A never touches LDS. A is 4 MB total, L2-resident (XCD sweeps
// rt fast), and the two wn-waves read identical A addresses -> L1 broadcast.
// Each wave loads its A fragments global->VGPR, register-prefetched one
// K-tile ahead (af[2][4], constant indices under full unroll).
// LDS = B only, double-buffered: 2 x 32 KB = 64 KB -> TWO blocks/CU
// (VGPR ~230 x 2 waves/SIMD = ~460 <= 512). Block A's barrier drain now
// overlaps block B's MFMA. LDS read volume per K-tile halves.
__global__ __launch_bounds__(256) void k_gemm_lse(const unsigned char* __restrict__ A,
                                                  const unsigned char* __restrict__ Bt,
                                                  float* __restrict__ m_part,
                                                  float* __restrict__ s_part) {
  extern __shared__ __align__(16) unsigned char sMemRaw[];  // 65536 B
#define SMB(buf) (sMemRaw + (buf) * 32768)
  float* maxbuf = (float*)sMemRaw;              // alias: dead after K-loop
  float* sumbuf = (float*)(sMemRaw + 2048);

  const int tid = threadIdx.x;
  // bijective XCD swizzle: 4000 blocks, 4000 % 8 == 0 -> chunks of 500/XCD.
  const int wg = ((int)blockIdx.x & 7) * ((RT_NUM * CT_NUM) / 8) + ((int)blockIdx.x >> 3);
  const int rt = wg & (RT_NUM - 1);   // RT_NUM = 32 (pow2), rt fast
  const int ct = wg >> 5;
  const int m0 = rt * BM;
  const int n0 = ct * BN;

  const int w = tid >> 6;
  const int l = tid & 63;
  const int wm = w >> 1;        // 0..1  (M: rows wm*64 .. +63)
  const int wn = w & 1;         // 0..1  (N: cols wn*128 .. +127)
  const int quad = l >> 4, lc = l & 15;

  f32x4 acc[4][8];
#pragma unroll
  for (int i = 0; i < 4; ++i)
#pragma unroll
    for (int j = 0; j < 8; ++j)
      acc[i][j] = (f32x4){0.f, 0.f, 0.f, 0.f};

  // B staging: one issue = 256 thr x 16B = 4KB = 32 rows of 128B; 8 issues.
  // Pre-swizzled global source column + linear LDS dest (m173): row r chunk c
  // holds global chunk c ^ (r&7).
  const int srow = tid >> 3;                               // 0..31
  const int scol = ((tid & 7) ^ (srow & 7)) * 16;
  const unsigned char* gb = Bt + (size_t)(n0 + srow) * H_DIM + scol;
  const int dOff = tid * 16;

  // B fragment read offsets (two swizzled b128 reads per frag)
  const int boff = wn * 16384 + lc * 128;  // + j*2048
  const int sw0 = ((quad * 2) ^ (lc & 7)) * 16;
  const int sw1 = ((quad * 2 + 1) ^ (lc & 7)) * 16;

  // A direct-load base: frag i covers rows m0 + wm*64 + i*16 + lc,
  // k-bytes kt*128 + quad*32 .. +31 (two dwordx4 at +0, +16).
  const unsigned char* pa = A + (size_t)(m0 + wm * 64 + lc) * H_DIM + quad * 32;

#define GLDS(gp, lp)                                                     \
  __builtin_amdgcn_global_load_lds(                                      \
      (const __attribute__((address_space(1))) void*)(gp),               \
      (__attribute__((address_space(3))) void*)(lp), 16, 0, 0)

#define STAGE8(buf, koff)                                                \
  do {                                                                   \
    _Pragma("unroll")                                                    \
    for (int i_ = 0; i_ < 8; ++i_)                                       \
      GLDS(gb + (size_t)i_ * 32 * H_DIM + (koff),                        \
           SMB(buf) + dOff + i_ * 4096);                                 \
  } while (0)

#define LDAG(dst, i, koff)                                               \
  do {                                                                   \
    const unsigned char* p_ = pa + (size_t)(i) * 16 * H_DIM + (koff);    \
    i32x4v lo_ = *(const i32x4v*)(p_);                                   \
    i32x4v hi_ = *(const i32x4v*)(p_ + 16);                              \
    dst = __builtin_shufflevector(lo_, hi_, 0, 1, 2, 3, 4, 5, 6, 7);     \
  } while (0)

#define LDB8(dst, buf, j)                                                \
  do {                                                                   \
    const unsigned char* p_ = SMB(buf) + (j) * 2048 + boff;              \
    i32x4v lo_ = *(const i32x4v*)(p_ + sw0);                             \
    i32x4v hi_ = *(const i32x4v*)(p_ + sw1);                             \
    dst = __builtin_shufflevector(lo_, hi_, 0, 1, 2, 3, 4, 5, 6, 7);     \
  } while (0)

  i32x8v af[2][4];

  // prologue: tile 0 (B -> LDS, A -> regs)
  STAGE8(0, 0);
  LDAG(af[0][0], 0, 0); LDAG(af[0][1], 1, 0);
  LDAG(af[0][2], 2, 0); LDAG(af[0][3], 3, 0);
  __syncthreads();

#pragma unroll
  for (int kt = 0; kt < NKT; ++kt) {
    const int cur = kt & 1;
    const int nk = cur ^ 1;
    if (kt < NKT - 1) {
      const int koff = (kt + 1) * BK;
      STAGE8(nk, koff);                      // aged prefetch: B -> LDS[nk]
      LDAG(af[nk][0], 0, koff); LDAG(af[nk][1], 1, koff);   // A -> regs
      LDAG(af[nk][2], 2, koff); LDAG(af[nk][3], 3, koff);
    }
#pragma unroll
    for (int j = 0; j < 8; ++j) {
      i32x8v bfj;
      LDB8(bfj, cur, j);
#pragma unroll
      for (int i = 0; i < 4; ++i)
        acc[i][j] = __builtin_amdgcn_mfma_scale_f32_16x16x128_f8f6f4(
            af[cur][i], bfj, acc[i][j], 0, 0, 0, SCALE1, 0, SCALE1);
    }
    __syncthreads();  // drains vmcnt (aged B staging + A prefetch) + lgkm;
                      // all waves past reading SMB(nk) -> safe to overwrite.
  }
#undef STAGE8
#undef GLDS
#undef LDAG
#undef LDB8

  // ---- epilogue: per-row max / sum-exp partials ----
  // C/D layout (shape-determined): col = lane&15, row = quad*4 + reg.
  // Global row of acc[i][*] reg r at lane(quad,lc): wm*64 + i*16 + quad*4 + r.
  float rmax[4][4];
#pragma unroll
  for (int i = 0; i < 4; ++i)
#pragma unroll
    for (int r = 0; r < 4; ++r) {
      float mx = acc[i][0][r];
#pragma unroll
      for (int j = 1; j < 8; ++j) mx = fmaxf(mx, acc[i][j][r]);
#pragma unroll
      for (int off = 1; off < 16; off <<= 1)
        mx = fmaxf(mx, __shfl_xor(mx, off, 64));
      rmax[i][r] = mx;
    }
  // sMem alias safe: the loop's final __syncthreads passed (all reads drained)
  if (lc == 0) {
#pragma unroll
    for (int i = 0; i < 4; ++i)
#pragma unroll
      for (int r = 0; r < 4; ++r)
        maxbuf[(wm * 64 + i * 16 + quad * 4 + r) * 2 + wn] = rmax[i][r];
  }
  __syncthreads();
  float rowmax[4][4];
#pragma unroll
  for (int i = 0; i < 4; ++i)
#pragma unroll
    for (int r = 0; r < 4; ++r) {
      int row = wm * 64 + i * 16 + quad * 4 + r;
      rowmax[i][r] = fmaxf(maxbuf[row * 2], maxbuf[row * 2 + 1]);
    }
#pragma unroll
  for (int i = 0; i < 4; ++i)
#pragma unroll
    for (int r = 0; r < 4; ++r) {
      float s = 0.f;
#pragma unroll
      for (int j = 0; j < 8; ++j) s += __expf(acc[i][j][r] - rowmax[i][r]);
#pragma unroll
      for (int off = 1; off < 16; off <<= 1)
        s += __shfl_xor(s, off, 64);
      if (lc == 0) sumbuf[(wm * 64 + i * 16 + quad * 4 + r) * 2 + wn] = s;
    }
  __syncthreads();
  if (wn == 0 && lc == 0) {
#pragma unroll
    for (int i = 0; i < 4; ++i)
#pragma unroll
      for (int r = 0; r < 4; ++r) {
        int row = wm * 64 + i * 16 + quad * 4 + r;
        size_t idx = (size_t)(m0 + row) * CT_NUM + ct;
        m_part[idx] = rowmax[i][r];
        s_part[idx] = sumbuf[row * 2] + sumbuf[row * 2 + 1];
      }
  }
#undef SMB
}

// ------------- combine partials + target logit -> per-block partial sums ----
__global__ __launch_bounds__(256) void k_combine(const float* __restrict__ x,
                                                 const unsigned char* __restrict__ wT8,
                                                 const int* __restrict__ target,
                                                 const float* __restrict__ m_part,
                                                 const float* __restrict__ s_part,
                                                 float* __restrict__ blk_part) {
  __shared__ float red[8];
  const int wv = threadIdx.x >> 6;
  const int row = blockIdx.x * 4 + wv;  // one wave per row
  const int l = threadIdx.x & 63;
  float m = -INFINITY, s = 0.f;
  for (int ctb = l; ctb < CT_NUM; ctb += 64) {
    float mj = m_part[(size_t)row * CT_NUM + ctb];
    float sj = s_part[(size_t)row * CT_NUM + ctb];
    float M = fmaxf(m, mj);
    s = s * __expf(m - M) + sj * __expf(mj - M);
    m = M;
  }
#pragma unroll
  for (int off = 1; off < 64; off <<= 1) {
    float mo = __shfl_xor(m, off, 64);
    float so = __shfl_xor(s, off, 64);
    float M = fmaxf(m, mo);
    s = s * __expf(m - M) + so * __expf(mo - M);
    m = M;
  }
  float lse = m + logf(s);
  int tgt = target[row];
  bool valid = (tgt != IGNORE_INDEX);
  int st = valid ? tgt : 0;
  // target logit: x[row] fp32 . wT8[st] fp8 (16 bytes per lane)
  const float* xr = x + (size_t)row * H_DIM + l * 16;
  int4 wv4 = *(const int4*)(wT8 + (size_t)st * H_DIM + l * 16);
  float t = 0.f;
#define ACC_DW(dw, base)                                              \
  t += xr[base + 0] * __builtin_amdgcn_cvt_f32_fp8(dw, 0);            \
  t += xr[base + 1] * __builtin_amdgcn_cvt_f32_fp8(dw, 1);            \
  t += xr[base + 2] * __builtin_amdgcn_cvt_f32_fp8(dw, 2);            \
  t += xr[base + 3] * __builtin_amdgcn_cvt_f32_fp8(dw, 3);
  ACC_DW(wv4.x, 0)
  ACC_DW(wv4.y, 4)
  ACC_DW(wv4.z, 8)
  ACC_DW(wv4.w, 12)
#undef ACC_DW
#pragma unroll
  for (int off = 1; off < 64; off <<= 1)
    t += __shfl_xor(t, off, 64);
  if (l == 0) {
    red[wv * 2]     = valid ? (lse - t) : 0.f;
    red[wv * 2 + 1] = valid ? lse : 0.f;
  }
  __syncthreads();
  if (threadIdx.x == 0) {
    blk_part[blockIdx.x * 2]     = red[0] + red[2] + red[4] + red[6];
    blk_part[blockIdx.x * 2 + 1] = red[1] + red[3] + red[5] + red[7];
  }
}

// ------------- final single-block reduce -------
__global__ __launch_bounds__(256) void k_final(const float* __restrict__ bp,
                                               float* __restrict__ out) {
  __shared__ float ra[4], rb[4];
  float a = 0.f, b = 0.f;
  for (int i = threadIdx.x; i < N_ROWS / 4; i += 256) {
    a += bp[i * 2];
    b += bp[i * 2 + 1];
  }
#pragma unroll
  for (int off = 1; off < 64; off <<= 1) {
    a += __shfl_xor(a, off, 64);
    b += __shfl_xor(b, off, 64);
  }
  if ((threadIdx.x & 63) == 0) { ra[threadIdx.x >> 6] = a; rb[threadIdx.x >> 6] = b; }
  __syncthreads();
  if (threadIdx.x == 0) {
    out[0] = ra[0] + ra[1] + ra[2] + ra[3];
    out[1] = rb[0] + rb[1] + rb[2] + rb[3];
  }
}

extern "C" void kernel_launch(void* const* d_in, const int* in_sizes, int n_in,
                              void* d_out, int out_size, void* d_ws, size_t ws_size,
                              hipStream_t stream) {
  const float* x = (const float*)d_in[0];
  const float* w = (const float*)d_in[1];
  const int* target = (const int*)d_in[2];
  float* out = (float*)d_out;

  static bool attr_set = false;
  if (!attr_set) {
    hipFuncSetAttribute(reinterpret_cast<const void*>(&k_gemm_lse),
                        hipFuncAttributeMaxDynamicSharedMemorySize, 65536);
    attr_set = true;
  }

  char* ws = (char*)d_ws;
  // ws layout:
  //   x8       : 4096*1024   =  4,194,304
  //   wT8      : 32000*1024  = 32,768,000
  //   m_part   : 4096*125*4  =  2,048,000
  //   s_part   : 4096*125*4  =  2,048,000
  //   blk_part : 1024*2*4    =      8,192
  unsigned char* x8 = (unsigned char*)ws;
  unsigned char* wT8 = (unsigned char*)(ws + 4194304);
  float* m_part = (float*)(ws + 4194304 + 32768000);
  float* s_part = (float*)(ws + 4194304 + 32768000 + 2048000);
  float* blk_part = (float*)(ws + 4194304 + 32768000 + 2048000 + 2048000);

  k_prep<<<dim3(XB8 + (V_DIM / 64) * (H_DIM / 128)), 256, 0, stream>>>(x, w, x8, wT8);
  k_gemm_lse<<<dim3(RT_NUM * CT_NUM), 256, 65536, stream>>>(x8, wT8, m_part, s_part);
  k_combine<<<dim3(N_ROWS / 4), 256, 0, stream>>>(x, wT8, target, m_part, s_part, blk_part);
  k_final<<<dim3(1), 256, 0, stream>>>(blk_part, out);
}

// Round 11
// 446.977 us; speedup vs baseline: 1.1366x; 1.1366x over previous
//
#include <hip/hip_runtime.h>
#include <hip/hip_bf16.h>

typedef float f32x4 __attribute__((ext_vector_type(4)));
typedef int i32x4v __attribute__((ext_vector_type(4)));
typedef int i32x8v __attribute__((ext_vector_type(8)));

#define IGNORE_INDEX (-100)
#define N_ROWS 4096
#define H_DIM  1024
#define V_DIM  32000

#define BM 128
#define BN 256
#define BK 128                 /* fp8 elements = bytes; one mfma_scale K */
#define NKT (H_DIM / BK)       /* 8 */
#define CT_NUM (V_DIM / BN)    /* 125 */
#define RT_NUM (N_ROWS / BM)   /* 32 */
#define SCALE1 0x7f7f7f7f      /* 4x e8m0 = 127 -> x1.0 */

// ---------- fused prep: cast x -> fp8 (blocks < XB8) + transpose-cast w ----------
#define XB8 (N_ROWS * H_DIM / (256 * 16))  /* 1024 */
__global__ __launch_bounds__(256) void k_prep(const float* __restrict__ x,
                                              const float* __restrict__ w,
                                              unsigned char* __restrict__ x8,
                                              unsigned char* __restrict__ wT8) {
  __shared__ float tile[128][65];
  const int t = threadIdx.x;
  if (blockIdx.x < XB8) {
    size_t i = ((size_t)blockIdx.x * 256 + t) * 16;
    const float4* xp = (const float4*)(x + i);
    float4 f0 = xp[0], f1 = xp[1], f2 = xp[2], f3 = xp[3];
    int4 o;
    int r;
    r = __builtin_amdgcn_cvt_pk_fp8_f32(f0.x, f0.y, 0, false);
    r = __builtin_amdgcn_cvt_pk_fp8_f32(f0.z, f0.w, r, true);
    o.x = r;
    r = __builtin_amdgcn_cvt_pk_fp8_f32(f1.x, f1.y, 0, false);
    r = __builtin_amdgcn_cvt_pk_fp8_f32(f1.z, f1.w, r, true);
    o.y = r;
    r = __builtin_amdgcn_cvt_pk_fp8_f32(f2.x, f2.y, 0, false);
    r = __builtin_amdgcn_cvt_pk_fp8_f32(f2.z, f2.w, r, true);
    o.z = r;
    r = __builtin_amdgcn_cvt_pk_fp8_f32(f3.x, f3.y, 0, false);
    r = __builtin_amdgcn_cvt_pk_fp8_f32(f3.z, f3.w, r, true);
    o.w = r;
    *(int4*)(x8 + i) = o;
    return;
  }
  const int b = blockIdx.x - XB8;
  const int v0 = (b % (V_DIM / 64)) * 64;
  const int k0 = (b / (V_DIM / 64)) * 128;
  {
    const int vq = t & 15;    // float4 index (16 x 4 = 64 floats/row)
    const int kr = t >> 4;    // 0..15
#pragma unroll
    for (int p = 0; p < 128; p += 16) {
      float4 v = *(const float4*)(w + (size_t)(k0 + kr + p) * V_DIM + v0 + vq * 4);
      tile[kr + p][vq * 4 + 0] = v.x;
      tile[kr + p][vq * 4 + 1] = v.y;
      tile[kr + p][vq * 4 + 2] = v.z;
      tile[kr + p][vq * 4 + 3] = v.w;
    }
  }
  __syncthreads();
  {
    const int vr = t >> 2;    // 0..63
    const int kq2 = t & 3;
#pragma unroll
    for (int h = 0; h < 2; ++h) {
      const int d4 = kq2 + h * 4;   // int4 index within 128B k-run
      int4 o;
      int r;
#pragma unroll
      for (int d = 0; d < 4; ++d) {
        r = __builtin_amdgcn_cvt_pk_fp8_f32(tile[d4 * 16 + d * 4 + 0][vr],
                                            tile[d4 * 16 + d * 4 + 1][vr], 0, false);
        r = __builtin_amdgcn_cvt_pk_fp8_f32(tile[d4 * 16 + d * 4 + 2][vr],
                                            tile[d4 * 16 + d * 4 + 3][vr], r, true);
        ((int*)&o)[d] = r;
      }
      *(int4*)(wT8 + (size_t)(v0 + vr) * H_DIM + k0 + d4 * 16) = o;
    }
  }
}

// ------------- fused MX-fp8 GEMM + per-row max/sumexp ------------------------
// R10 LESSONS: (a) this kernel is pinned at 1 block/CU regardless of LDS
// (96KB R8 -> 64KB R10: Occupancy 11% both) — occupancy is a dead lever;
// (b) A-direct-to-VGPR regressed (335us, MfmaUtil 16%): per-lane A latency
// joined the per-tile drain; (c) arithmetic: LDS fragment reads are
// 96KB/tile/CU ~= 1130cyc ~= MFMA 1100cyc — balanced — but R8's 4900cyc/tile
// means ~2600cyc/tile of drain stall (depth-1 pipeline, vmcnt(0) every tile).
//
// THIS ROUND: A+B back in LDS (R8 layout), pipeline depth 2 with counted
// vmcnt and ONE raw barrier per K-tile:
//   triple-buffer LDS (3 x 48KB = 144KB);
//   per tile: vmcnt(12) [waits only the tile issued TWO iterations ago,
//   aged >=2200cyc >> 900cyc HBM] -> s_barrier -> issue tile kt+2's 12
//   global_load_lds -> ds_read frags -> 32 MFMA. Never vmcnt(0) in steady
//   state (AITER pattern). Race-free with one barrier: a wave passes BAR(kt)
//   only after its kt-1 ds_reads returned (lgkm waits precede MFMA use), and
//   buf[(kt+2)%3] was last read in iteration kt-1.
__global__ __launch_bounds__(256) void k_gemm_lse(const unsigned char* __restrict__ A,
                                                  const unsigned char* __restrict__ Bt,
                                                  float* __restrict__ m_part,
                                                  float* __restrict__ s_part) {
  extern __shared__ __align__(16) unsigned char sMemRaw[];  // 147456 B
#define SMA(buf) (sMemRaw + (buf) * 49152)
#define SMB(buf) (sMemRaw + (buf) * 49152 + 16384)
  float* maxbuf = (float*)sMemRaw;              // alias buf0-A: dead after loop
  float* sumbuf = (float*)(sMemRaw + 2048);

  const int tid = threadIdx.x;
  // bijective XCD swizzle: 4000 blocks, 4000 % 8 == 0 -> chunks of 500/XCD.
  const int wg = ((int)blockIdx.x & 7) * ((RT_NUM * CT_NUM) / 8) + ((int)blockIdx.x >> 3);
  const int rt = wg & (RT_NUM - 1);   // RT_NUM = 32 (pow2), rt fast
  const int ct = wg >> 5;
  const int m0 = rt * BM;
  const int n0 = ct * BN;

  const int w = tid >> 6;
  const int l = tid & 63;
  const int wm = w >> 1;        // 0..1  (M: rows wm*64 .. +63)
  const int wn = w & 1;         // 0..1  (N: cols wn*128 .. +127)
  const int quad = l >> 4, lc = l & 15;

  f32x4 acc[4][8];
#pragma unroll
  for (int i = 0; i < 4; ++i)
#pragma unroll
    for (int j = 0; j < 8; ++j)
      acc[i][j] = (f32x4){0.f, 0.f, 0.f, 0.f};

  // staging: one issue = 256 thr x 16B = 4KB = 32 rows of 128B.
  // A (128 rows) = 4 issues; B (256 rows) = 8 issues; 12 glds/thread/tile.
  // Pre-swizzled global source column + linear LDS dest (m173).
  const int srow = tid >> 3;                               // 0..31
  const int scol = ((tid & 7) ^ (srow & 7)) * 16;
  const unsigned char* ga = A + (size_t)(m0 + srow) * H_DIM + scol;
  const unsigned char* gb = Bt + (size_t)(n0 + srow) * H_DIM + scol;
  const int dOff = tid * 16;

  // fragment read offsets (two swizzled b128 reads per frag; row&7 == lc&7)
  const int aoff = wm * 8192 + lc * 128;   // + i*2048
  const int boff = wn * 16384 + lc * 128;  // + j*2048
  const int sw0 = ((quad * 2) ^ (lc & 7)) * 16;
  const int sw1 = ((quad * 2 + 1) ^ (lc & 7)) * 16;

#define GLDS(gp, lp)                                                     \
  __builtin_amdgcn_global_load_lds(                                      \
      (const __attribute__((address_space(1))) void*)(gp),               \
      (__attribute__((address_space(3))) void*)(lp), 16, 0, 0)

#define STAGE12(buf, koff)                                               \
  do {                                                                   \
    _Pragma("unroll")                                                    \
    for (int i_ = 0; i_ < 4; ++i_)                                       \
      GLDS(ga + (size_t)i_ * 32 * H_DIM + (koff),                        \
           SMA(buf) + dOff + i_ * 4096);                                 \
    _Pragma("unroll")                                                    \
    for (int i_ = 0; i_ < 8; ++i_)                                       \
      GLDS(gb + (size_t)i_ * 32 * H_DIM + (koff),                        \
           SMB(buf) + dOff + i_ * 4096);                                 \
  } while (0)

#define LDA8(dst, buf, i)                                                \
  do {                                                                   \
    const unsigned char* p_ = SMA(buf) + (i) * 2048 + aoff;              \
    i32x4v lo_ = *(const i32x4v*)(p_ + sw0);                             \
    i32x4v hi_ = *(const i32x4v*)(p_ + sw1);                             \
    dst = __builtin_shufflevector(lo_, hi_, 0, 1, 2, 3, 4, 5, 6, 7);     \
  } while (0)

#define LDB8(dst, buf, j)                                                \
  do {                                                                   \
    const unsigned char* p_ = SMB(buf) + (j) * 2048 + boff;              \
    i32x4v lo_ = *(const i32x4v*)(p_ + sw0);                             \
    i32x4v hi_ = *(const i32x4v*)(p_ + sw1);                             \
    dst = __builtin_shufflevector(lo_, hi_, 0, 1, 2, 3, 4, 5, 6, 7);     \
  } while (0)

#define FENCE() asm volatile("" ::: "memory")
#define BAR() do { __builtin_amdgcn_s_barrier(); FENCE(); } while (0)
#define VMW(n) asm volatile("s_waitcnt vmcnt(" #n ")" ::: "memory")

  // prologue: stage tiles 0 and 1 (issue order defines vmcnt retirement order)
  STAGE12(0, 0);
  STAGE12(1, BK);

#pragma unroll
  for (int kt = 0; kt < NKT; ++kt) {
    // wait ONLY the oldest in-flight tile (issued 2 iterations ago);
    // tail kt==NKT-1 has just 12 outstanding -> full drain is free there.
    if (kt < NKT - 1) { VMW(12); } else { VMW(0); }
    BAR();   // all waves see tile kt resident; all waves done reading
             // buf[(kt+2)%3] (== buf[(kt-1)%3]) from iteration kt-1.
    if (kt + 2 < NKT) STAGE12((kt + 2) % 3, (kt + 2) * BK);

    const int cur = kt % 3;
    i32x8v af[4];
    LDA8(af[0], cur, 0); LDA8(af[1], cur, 1);
    LDA8(af[2], cur, 2); LDA8(af[3], cur, 3);
#pragma unroll
    for (int j = 0; j < 8; ++j) {
      i32x8v bfj;
      LDB8(bfj, cur, j);
#pragma unroll
      for (int i = 0; i < 4; ++i)
        acc[i][j] = __builtin_amdgcn_mfma_scale_f32_16x16x128_f8f6f4(
            af[i], bfj, acc[i][j], 0, 0, 0, SCALE1, 0, SCALE1);
    }
    // no trailing barrier: next iteration's top BAR provides the sync.
  }
#undef STAGE12
#undef GLDS
#undef LDA8
#undef LDB8

  // ---- epilogue: per-row max / sum-exp partials ----
  // C/D layout (shape-determined): col = lane&15, row = quad*4 + reg.
  // Global row of acc[i][*] reg r at lane(quad,lc): wm*64 + i*16 + quad*4 + r.
  // maxbuf/sumbuf alias buf0's A region (2KB); tile 7 reads use buf1 -> no
  // address overlap with concurrent laggard waves; __syncthreads below syncs.
  float rmax[4][4];
#pragma unroll
  for (int i = 0; i < 4; ++i)
#pragma unroll
    for (int r = 0; r < 4; ++r) {
      float mx = acc[i][0][r];
#pragma unroll
      for (int j = 1; j < 8; ++j) mx = fmaxf(mx, acc[i][j][r]);
#pragma unroll
      for (int off = 1; off < 16; off <<= 1)
        mx = fmaxf(mx, __shfl_xor(mx, off, 64));
      rmax[i][r] = mx;
    }
  if (lc == 0) {
#pragma unroll
    for (int i = 0; i < 4; ++i)
#pragma unroll
      for (int r = 0; r < 4; ++r)
        maxbuf[(wm * 64 + i * 16 + quad * 4 + r) * 2 + wn] = rmax[i][r];
  }
  __syncthreads();
  float rowmax[4][4];
#pragma unroll
  for (int i = 0; i < 4; ++i)
#pragma unroll
    for (int r = 0; r < 4; ++r) {
      int row = wm * 64 + i * 16 + quad * 4 + r;
      rowmax[i][r] = fmaxf(maxbuf[row * 2], maxbuf[row * 2 + 1]);
    }
#pragma unroll
  for (int i = 0; i < 4; ++i)
#pragma unroll
    for (int r = 0; r < 4; ++r) {
      float s = 0.f;
#pragma unroll
      for (int j = 0; j < 8; ++j) s += __expf(acc[i][j][r] - rowmax[i][r]);
#pragma unroll
      for (int off = 1; off < 16; off <<= 1)
        s += __shfl_xor(s, off, 64);
      if (lc == 0) sumbuf[(wm * 64 + i * 16 + quad * 4 + r) * 2 + wn] = s;
    }
  __syncthreads();
  if (wn == 0 && lc == 0) {
#pragma unroll
    for (int i = 0; i < 4; ++i)
#pragma unroll
      for (int r = 0; r < 4; ++r) {
        int row = wm * 64 + i * 16 + quad * 4 + r;
        size_t idx = (size_t)(m0 + row) * CT_NUM + ct;
        m_part[idx] = rowmax[i][r];
        s_part[idx] = sumbuf[row * 2] + sumbuf[row * 2 + 1];
      }
  }
#undef SMA
#undef SMB
}

// ------------- combine partials + target logit -> per-block partial sums ----
__global__ __launch_bounds__(256) void k_combine(const float* __restrict__ x,
                                                 const unsigned char* __restrict__ wT8,
                                                 const int* __restrict__ target,
                                                 const float* __restrict__ m_part,
                                                 const float* __restrict__ s_part,
                                                 float* __restrict__ blk_part) {
  __shared__ float red[8];
  const int wv = threadIdx.x >> 6;
  const int row = blockIdx.x * 4 + wv;  // one wave per row
  const int l = threadIdx.x & 63;
  float m = -INFINITY, s = 0.f;
  for (int ctb = l; ctb < CT_NUM; ctb += 64) {
    float mj = m_part[(size_t)row * CT_NUM + ctb];
    float sj = s_part[(size_t)row * CT_NUM + ctb];
    float M = fmaxf(m, mj);
    s = s * __expf(m - M) + sj * __expf(mj - M);
    m = M;
  }
#pragma unroll
  for (int off = 1; off < 64; off <<= 1) {
    float mo = __shfl_xor(m, off, 64);
    float so = __shfl_xor(s, off, 64);
    float M = fmaxf(m, mo);
    s = s * __expf(m - M) + so * __expf(mo - M);
    m = M;
  }
  float lse = m + logf(s);
  int tgt = target[row];
  bool valid = (tgt != IGNORE_INDEX);
  int st = valid ? tgt : 0;
  // target logit: x[row] fp32 . wT8[st] fp8 (16 bytes per lane)
  const float* xr = x + (size_t)row * H_DIM + l * 16;
  int4 wv4 = *(const int4*)(wT8 + (size_t)st * H_DIM + l * 16);
  float t = 0.f;
#define ACC_DW(dw, base)                                              \
  t += xr[base + 0] * __builtin_amdgcn_cvt_f32_fp8(dw, 0);            \
  t += xr[base + 1] * __builtin_amdgcn_cvt_f32_fp8(dw, 1);            \
  t += xr[base + 2] * __builtin_amdgcn_cvt_f32_fp8(dw, 2);            \
  t += xr[base + 3] * __builtin_amdgcn_cvt_f32_fp8(dw, 3);
  ACC_DW(wv4.x, 0)
  ACC_DW(wv4.y, 4)
  ACC_DW(wv4.z, 8)
  ACC_DW(wv4.w, 12)
#undef ACC_DW
#pragma unroll
  for (int off = 1; off < 64; off <<= 1)
    t += __shfl_xor(t, off, 64);
  if (l == 0) {
    red[wv * 2]     = valid ? (lse - t) : 0.f;
    red[wv * 2 + 1] = valid ? lse : 0.f;
  }
  __syncthreads();
  if (threadIdx.x == 0) {
    blk_part[blockIdx.x * 2]     = red[0] + red[2] + red[4] + red[6];
    blk_part[blockIdx.x * 2 + 1] = red[1] + red[3] + red[5] + red[7];
  }
}

// ------------- final single-block reduce -------
__global__ __launch_bounds__(256) void k_final(const float* __restrict__ bp,
                                               float* __restrict__ out) {
  __shared__ float ra[4], rb[4];
  float a = 0.f, b = 0.f;
  for (int i = threadIdx.x; i < N_ROWS / 4; i += 256) {
    a += bp[i * 2];
    b += bp[i * 2 + 1];
  }
#pragma unroll
  for (int off = 1; off < 64; off <<= 1) {
    a += __shfl_xor(a, off, 64);
    b += __shfl_xor(b, off, 64);
  }
  if ((threadIdx.x & 63) == 0) { ra[threadIdx.x >> 6] = a; rb[threadIdx.x >> 6] = b; }
  __syncthreads();
  if (threadIdx.x == 0) {
    out[0] = ra[0] + ra[1] + ra[2] + ra[3];
    out[1] = rb[0] + rb[1] + rb[2] + rb[3];
  }
}

extern "C" void kernel_launch(void* const* d_in, const int* in_sizes, int n_in,
                              void* d_out, int out_size, void* d_ws, size_t ws_size,
                              hipStream_t stream) {
  const float* x = (const float*)d_in[0];
  const float* w = (const float*)d_in[1];
  const int* target = (const int*)d_in[2];
  float* out = (float*)d_out;

  static bool attr_set = false;
  if (!attr_set) {
    hipFuncSetAttribute(reinterpret_cast<const void*>(&k_gemm_lse),
                        hipFuncAttributeMaxDynamicSharedMemorySize, 147456);
    attr_set = true;
  }

  char* ws = (char*)d_ws;
  // ws layout:
  //   x8       : 4096*1024   =  4,194,304
  //   wT8      : 32000*1024  = 32,768,000
  //   m_part   : 4096*125*4  =  2,048,000
  //   s_part   : 4096*125*4  =  2,048,000
  //   blk_part : 1024*2*4    =      8,192
  unsigned char* x8 = (unsigned char*)ws;
  unsigned char* wT8 = (unsigned char*)(ws + 4194304);
  float* m_part = (float*)(ws + 4194304 + 32768000);
  float* s_part = (float*)(ws + 4194304 + 32768000 + 2048000);
  float* blk_part = (float*)(ws + 4194304 + 32768000 + 2048000 + 2048000);

  k_prep<<<dim3(XB8 + (V_DIM / 64) * (H_DIM / 128)), 256, 0, stream>>>(x, w, x8, wT8);
  k_gemm_lse<<<dim3(RT_NUM * CT_NUM), 256, 147456, stream>>>(x8, wT8, m_part, s_part);
  k_combine<<<dim3(N_ROWS / 4), 256, 0, stream>>>(x, wT8, target, m_part, s_part, blk_part);
  k_final<<<dim3(1), 256, 0, stream>>>(blk_part, out);
}